// Round 9
// baseline (159.292 us; speedup 1.0000x reference)
//
#include <hip/hip_runtime.h>

typedef short short8_t __attribute__((ext_vector_type(8)));
typedef float floatx16 __attribute__((ext_vector_type(16)));

#define H_ 8
#define B_ 4
#define N_ 2048
#define D_ 64
#define EPS_ 0.0009765625f
#define LOG2E 1.44269504088896340736f

// ---- ws layout (bytes) ----
#define CNT_OFF   0                      // 4 int
#define IDX_OFF   256                    // [4][2048] int: unmasked indices
#define ZIDX_OFF  33024                  // [4][2048] int: masked indices
#define KHI_OFF   65792                  // [32][2048][64] bf16 (K*log2e hi)
#define KLO_OFF   (KHI_OFF + 8388608)
#define VT_OFF    (KLO_OFF + 8388608)    // [32][64][2048] bf16 V^T
#define K2_OFF    (VT_OFF + 8388608)     // [32][2048] f32 (-0.5*log2e*k2)

// split a pair of floats into bf16 hi + bf16 residual-lo words via cvt_pk
__device__ __forceinline__ void bfsplit2(float a0, float a1,
                                         unsigned int& hi, unsigned int& lo) {
    unsigned int ph;
    asm("v_cvt_pk_bf16_f32 %0, %1, %2" : "=v"(ph) : "v"(a0), "v"(a1));
    const float h0 = __uint_as_float(ph << 16);
    const float h1 = __uint_as_float(ph & 0xFFFF0000u);
    const float r0 = a0 - h0, r1 = a1 - h1;
    unsigned int pl;
    asm("v_cvt_pk_bf16_f32 %0, %1, %2" : "=v"(pl) : "v"(r0), "v"(r1));
    hi = ph; lo = pl;
}

// ---------------------------------------------------------------------------
// Convert kernel with inline mask compaction.
// Grid (32 j-tiles, 32 planes). Each block: detect mask format, per-batch
// ordered prefix-scan (serial in t0 — ~1us), gather its 64-key window,
// convert K -> bf16 hi/lo of K*log2e, V -> bf16 V^T, k2 -> -0.5*log2e*k2.
// Blocks (j0==0, p<4) additionally publish cnt/idx/zidx for the attn kernel.
// ---------------------------------------------------------------------------
__global__ __launch_bounds__(256) void convert_kernel(
    const float* __restrict__ Kg, const float* __restrict__ Vg,
    const void* __restrict__ mask, unsigned char* __restrict__ ws) {
    __shared__ int okInt, okFloat;
    __shared__ int pre[257], zpre[257];
    __shared__ int lidx[64];
    __shared__ unsigned short Vb[64][68];   // stride 68 shorts: u32-aligned rows

    const int p = blockIdx.y;
    const int head = p >> 2, b = p & 3;
    const int j0 = blockIdx.x * 64;
    const int t = threadIdx.x;

    // ---- mask format detection (words [0,512) valid under u8/i32/f32) ----
    if (t == 0) { okInt = 1; okFloat = 1; }
    __syncthreads();
    {
        const unsigned int* w = (const unsigned int*)mask;
        int badI = 0, badF = 0;
        for (int i = t; i < 512; i += 256) {
            const unsigned int x = w[i];
            if (x > 1u) badI = 1;
            if (x != 0u && x != 0x3F800000u) badF = 1;
        }
        if (badI) atomicAnd(&okInt, 0);
        if (badF) atomicAnd(&okFloat, 0);
    }
    __syncthreads();

    // ---- per-thread mask bits for batch b ----
    int loc[8];
    const int e0 = b * N_ + t * 8;
    if (okInt) {
        const int* q = (const int*)mask;
#pragma unroll
        for (int i = 0; i < 8; ++i) loc[i] = (q[e0 + i] != 0) ? 1 : 0;
    } else if (okFloat) {
        const float* q = (const float*)mask;
#pragma unroll
        for (int i = 0; i < 8; ++i) loc[i] = (q[e0 + i] != 0.0f) ? 1 : 0;
    } else {
        const unsigned char* q = (const unsigned char*)mask;
#pragma unroll
        for (int i = 0; i < 8; ++i) loc[i] = q[e0 + i] ? 1 : 0;
    }
    int c = 0;
#pragma unroll
    for (int i = 0; i < 8; ++i) c += loc[i];
    pre[t + 1] = c;
    zpre[t + 1] = 8 - c;
    __syncthreads();
    if (t == 0) {
        pre[0] = 0; zpre[0] = 0;
        for (int i = 1; i <= 256; ++i) { pre[i] += pre[i - 1]; zpre[i] += zpre[i - 1]; }
    }
    __syncthreads();
    const int kcnt = pre[256];

    // ---- designated blocks publish cnt / idx / zidx for attn ----
    if (j0 == 0 && p < 4) {
        int* ob = (int*)(ws + IDX_OFF) + b * N_;
        int* zb = (int*)(ws + ZIDX_OFF) + b * N_;
        int u = pre[t], z = zpre[t];
#pragma unroll
        for (int i = 0; i < 8; ++i) {
            if (loc[i]) ob[u++] = t * 8 + i;
            else        zb[z++] = t * 8 + i;
        }
        if (t == 0) ((int*)(ws + CNT_OFF))[b] = kcnt;
    }
    if (j0 >= kcnt) return;   // uniform: this key tile never read

    // ---- gather this block's 64-key window into lidx ----
    {
        int u = pre[t];
#pragma unroll
        for (int i = 0; i < 8; ++i) {
            if (loc[i]) {
                if ((unsigned)(u - j0) < 64u) lidx[u - j0] = t * 8 + i;
                ++u;
            }
        }
    }
    __syncthreads();

    // ---- conversion ----
    const int jl = t >> 2, c4 = t & 3;
    const int j = j0 + jl;
    const size_t plane_f = (size_t)head * ((size_t)B_ * N_ * D_) + (size_t)b * (N_ * D_);

    float kv[16], vv[16];
    if (j < kcnt) {
        const int ki = lidx[jl];
        const float4* kr = (const float4*)(Kg + plane_f + (size_t)ki * D_ + 16 * c4);
        const float4* vr = (const float4*)(Vg + plane_f + (size_t)ki * D_ + 16 * c4);
#pragma unroll
        for (int i = 0; i < 4; ++i) {
            float4 a = kr[i]; float4 v = vr[i];
            kv[4*i] = a.x; kv[4*i+1] = a.y; kv[4*i+2] = a.z; kv[4*i+3] = a.w;
            vv[4*i] = v.x; vv[4*i+1] = v.y; vv[4*i+2] = v.z; vv[4*i+3] = v.w;
        }
    } else {
#pragma unroll
        for (int i = 0; i < 16; ++i) { kv[i] = 0.f; vv[i] = 0.f; }
    }
    float k2 = 0.f;
    unsigned int khi[8], klo[8];
#pragma unroll
    for (int i = 0; i < 8; ++i) {
        const float a0 = kv[2*i], a1 = kv[2*i+1];
        k2 = fmaf(a0, a0, k2); k2 = fmaf(a1, a1, k2);
        bfsplit2(a0 * LOG2E, a1 * LOG2E, khi[i], klo[i]);   // K pre-scaled by log2e
    }
    k2 += __shfl_xor(k2, 1);
    k2 += __shfl_xor(k2, 2);
    {
        unsigned char* dh = ws + KHI_OFF + ((size_t)p * N_ + j) * 128 + 32 * c4;
        unsigned char* dl = ws + KLO_OFF + ((size_t)p * N_ + j) * 128 + 32 * c4;
        ((uint4*)dh)[0] = make_uint4(khi[0], khi[1], khi[2], khi[3]);
        ((uint4*)dh)[1] = make_uint4(khi[4], khi[5], khi[6], khi[7]);
        ((uint4*)dl)[0] = make_uint4(klo[0], klo[1], klo[2], klo[3]);
        ((uint4*)dl)[1] = make_uint4(klo[4], klo[5], klo[6], klo[7]);
        if (c4 == 0) ((float*)(ws + K2_OFF))[(size_t)p * N_ + j] = -0.5f * LOG2E * k2;
    }
#pragma unroll
    for (int i = 0; i < 8; ++i) {   // V -> bf16 (packed pair writes)
        unsigned int pv;
        asm("v_cvt_pk_bf16_f32 %0, %1, %2" : "=v"(pv) : "v"(vv[2*i]), "v"(vv[2*i+1]));
        *(unsigned int*)&Vb[jl][16 * c4 + 2 * i] = pv;
    }
    __syncthreads();
    {   // transposed write: VT row d = jl, cols j0+16c4..+15
        unsigned int wds[8];
#pragma unroll
        for (int i = 0; i < 8; ++i)
            wds[i] = (unsigned int)Vb[16*c4 + 2*i][jl] | ((unsigned int)Vb[16*c4 + 2*i + 1][jl] << 16);
        unsigned char* dv = ws + VT_OFF + ((size_t)p * 64 + jl) * ((size_t)N_ * 2) + (size_t)(j0 + 16 * c4) * 2;
        ((uint4*)dv)[0] = make_uint4(wds[0], wds[1], wds[2], wds[3]);
        ((uint4*)dv)[1] = make_uint4(wds[4], wds[5], wds[6], wds[7]);
    }
}

// ---------------------------------------------------------------------------
// MFMA attention, compacted q & k, fused zero-fill epilogue.
// 4 waves = 2x2 32x32 quadrants. QK^T: split-bf16 into 3 INDEPENDENT
// accumulators (HH/HL/LH); PV: 2 accumulators. Q frags hoisted to registers.
// exp via raw v_exp_f32 (K pre-scaled by log2e); pads masked via k2=-1e30.
// W -> bf16 via v_cvt_pk_bf16_f32 pairs.
// C/D layout (m74/m101): col=lane&31, row=(reg&3)+8*(reg>>2)+4*(lane>>5).
// Every jq in [0,N) maps to exactly one output row: idx[jq] (attn result)
// or zidx[jq-kcnt] (explicit zero) — replaces the zero_kernel.
// ---------------------------------------------------------------------------
__global__ __launch_bounds__(256, 2) void hept_mfma_kernel(
    const float* __restrict__ Qg, const unsigned char* __restrict__ ws,
    float* __restrict__ Out) {
    __shared__ __align__(16) unsigned short Qhi[4096], Qlo[4096], Khi[4096],
                                            Klo[4096], Vt[4096], Wt[4096];
    __shared__ float q2s[64], k2t[64], dpart[2][64];
    __shared__ int qidx_s[64];

    const int t = threadIdx.x;
    const int l = t & 63;
    const int w = t >> 6;
    const int qh = w >> 1, kh = w & 1;

    // XCD swizzle: 4 consecutive planes per XCD
    const int cid = blockIdx.x;
    const int swz = (cid & 7) * 128 + (cid >> 3);
    const int p = swz >> 5;
    const int qb = swz & 31;
    const int head = p >> 2, b = p & 3;
    const int q0 = qb * 64;

    const int kcnt = ((const int*)(ws + CNT_OFF))[b];
    const int* idxb = (const int*)(ws + IDX_OFF) + b * N_;
    const int* zidxb = (const int*)(ws + ZIDX_OFF) + b * N_;
    const bool active = (q0 < kcnt);
    const int nt = active ? ((kcnt + 63) >> 6) : 0;

    const size_t plane_f = (size_t)head * ((size_t)B_ * N_ * D_) + (size_t)b * (N_ * D_);
    const unsigned short* khi_g = (const unsigned short*)(ws + KHI_OFF) + (size_t)p * ((size_t)N_ * 64);
    const unsigned short* klo_g = (const unsigned short*)(ws + KLO_OFF) + (size_t)p * ((size_t)N_ * 64);
    const unsigned short* vt_g  = (const unsigned short*)(ws + VT_OFF)  + (size_t)p * ((size_t)64 * N_);
    const float* k2_g = (const float*)(ws + K2_OFF) + (size_t)p * N_;

    // ---- prologue: output row map; gather+split Q (active only) ----
    if (t < 64) {
        const int jq = q0 + t;
        qidx_s[t] = (jq < kcnt) ? idxb[jq] : zidxb[jq - kcnt];
    }
    if (active) {
        const int row = t >> 2, c4 = t & 3;
        const int jq = q0 + row;
        const int qi = (jq < kcnt) ? idxb[jq] : idxb[0];
        const float4* qr = (const float4*)(Qg + plane_f + (size_t)qi * D_ + 16 * c4);
        float q[16];
#pragma unroll
        for (int i = 0; i < 4; ++i) {
            float4 a = qr[i];
            q[4*i] = a.x; q[4*i+1] = a.y; q[4*i+2] = a.z; q[4*i+3] = a.w;
        }
        float q2 = 0.f;
        unsigned int hi[8], lo[8];
#pragma unroll
        for (int i = 0; i < 8; ++i) {
            const float a0 = q[2*i], a1 = q[2*i+1];
            q2 = fmaf(a0, a0, q2); q2 = fmaf(a1, a1, q2);
            bfsplit2(a0, a1, hi[i], lo[i]);          // Q stays UNSCALED
        }
        q2 += __shfl_xor(q2, 1);
        q2 += __shfl_xor(q2, 2);
        if (c4 == 0) q2s[row] = -0.5f * LOG2E * q2;
        const int s0 = (2 * c4) ^ (row & 7);
        const int s1 = (2 * c4 + 1) ^ (row & 7);
        *(uint4*)&Qhi[row * 64 + 8 * s0] = make_uint4(hi[0], hi[1], hi[2], hi[3]);
        *(uint4*)&Qhi[row * 64 + 8 * s1] = make_uint4(hi[4], hi[5], hi[6], hi[7]);
        *(uint4*)&Qlo[row * 64 + 8 * s0] = make_uint4(lo[0], lo[1], lo[2], lo[3]);
        *(uint4*)&Qlo[row * 64 + 8 * s1] = make_uint4(lo[4], lo[5], lo[6], lo[7]);
    }
    __syncthreads();

    // per-lane frag offsets (ushort index); identical pattern A and B sides
    const int rowA = 32 * qh + (l & 31);
    const int rowB = 32 * kh + (l & 31);
    const int g = l >> 5;
    int offA[4], offB[4];
#pragma unroll
    for (int ks = 0; ks < 4; ++ks) {
        offA[ks] = rowA * 64 + 8 * ((2 * ks + g) ^ (rowA & 7));
        offB[ks] = rowB * 64 + 8 * ((2 * ks + g) ^ (rowB & 7));
    }
    // hoisted Q fragments (tile-invariant)
    short8_t qHf[4], qLf[4];
#pragma unroll
    for (int ks = 0; ks < 4; ++ks) {
        qHf[ks] = *(const short8_t*)&Qhi[offA[ks]];
        qLf[ks] = *(const short8_t*)&Qlo[offA[ks]];
    }
    float q2r[16];
#pragma unroll
    for (int r = 0; r < 16; ++r)
        q2r[r] = q2s[32 * qh + (r & 3) + 8 * (r >> 2) + 4 * g];

    // staging geometry: wave w covers 1KB chunks {2w,2w+1}; pre-swizzled src
    const int rch = l >> 3;
    const int sl8 = (l & 7) ^ rch;
    const int ch0 = 2 * w, ch1 = 2 * w + 1;
    const unsigned short* srcK0 = khi_g + (size_t)(ch0 * 8 + rch) * 64 + 8 * sl8;
    const unsigned short* srcK1 = khi_g + (size_t)(ch1 * 8 + rch) * 64 + 8 * sl8;
    const unsigned short* srcL0 = klo_g + (size_t)(ch0 * 8 + rch) * 64 + 8 * sl8;
    const unsigned short* srcL1 = klo_g + (size_t)(ch1 * 8 + rch) * 64 + 8 * sl8;
    const unsigned short* srcV0 = vt_g + (size_t)(ch0 * 8 + rch) * N_ + 8 * sl8;
    const unsigned short* srcV1 = vt_g + (size_t)(ch1 * 8 + rch) * N_ + 8 * sl8;
    const int dstA = ch0 * 512 + 8 * l;
    const int dstB = ch1 * 512 + 8 * l;

    floatx16 oaccA, oaccB;
    float dsum[16];
#pragma unroll
    for (int r = 0; r < 16; ++r) { oaccA[r] = 0.f; oaccB[r] = 0.f; dsum[r] = 0.f; }
    const int keycol = 32 * kh + (l & 31);
    const int slotbase = keycol >> 3;
    const int crem = keycol & 7;

    uint4 rA0, rA1, rB0, rB1, rC0, rC1;
    float rk2;
#define LOADT(kt_) do { \
        const size_t o_ = (size_t)(kt_) * 4096; \
        const size_t ov_ = (size_t)(kt_) * 64; \
        rA0 = *(const uint4*)(srcK0 + o_); rA1 = *(const uint4*)(srcK1 + o_); \
        rB0 = *(const uint4*)(srcL0 + o_); rB1 = *(const uint4*)(srcL1 + o_); \
        rC0 = *(const uint4*)(srcV0 + ov_); rC1 = *(const uint4*)(srcV1 + ov_); \
        rk2 = -1e30f; \
        if (t < 64) { \
            const int pos_ = (kt_) * 64 + t; \
            const float v_ = k2_g[pos_]; \
            rk2 = (pos_ < kcnt) ? v_ : -1e30f; \
        } \
    } while (0)

    if (nt > 0) LOADT(0);
    for (int kt = 0; kt < nt; ++kt) {
        __syncthreads();   // barA: prev tile's frag reads done -> LDS free
        *(uint4*)&Khi[dstA] = rA0;  *(uint4*)&Khi[dstB] = rA1;
        *(uint4*)&Klo[dstA] = rB0;  *(uint4*)&Klo[dstB] = rB1;
        *(uint4*)&Vt[dstA]  = rC0;  *(uint4*)&Vt[dstB]  = rC1;
        if (t < 64) k2t[t] = rk2;
        __syncthreads();   // barB: staged
        if (kt + 1 < nt) LOADT(kt + 1);  // prefetch hides under QK+exp

        // ---- QK^T: 3 independent accumulator chains ----
        floatx16 aHH, aHL, aLH;
#pragma unroll
        for (int r = 0; r < 16; ++r) { aHH[r] = 0.f; aHL[r] = 0.f; aLH[r] = 0.f; }
#pragma unroll
        for (int ks = 0; ks < 4; ++ks) {
            short8_t kH = *(const short8_t*)&Khi[offB[ks]];
            short8_t kL = *(const short8_t*)&Klo[offB[ks]];
            aHH = __builtin_amdgcn_mfma_f32_32x32x16_bf16(qHf[ks], kH, aHH, 0, 0, 0);
            aHL = __builtin_amdgcn_mfma_f32_32x32x16_bf16(qHf[ks], kL, aHL, 0, 0, 0);
            aLH = __builtin_amdgcn_mfma_f32_32x32x16_bf16(qLf[ks], kH, aLH, 0, 0, 0);
        }

        // ---- w = 2^(qk*log2e - (q2+k2)*log2e/2); pads have k2=-1e30 ----
        const float k2v = k2t[keycol];
#pragma unroll
        for (int i = 0; i < 8; ++i) {
            const int r0 = 2 * i, r1 = 2 * i + 1;
            const float x0 = (aHH[r0] + aHL[r0]) + (aLH[r0] + (q2r[r0] + k2v));
            const float x1 = (aHH[r1] + aHL[r1]) + (aLH[r1] + (q2r[r1] + k2v));
            float e0, e1;
            asm("v_exp_f32 %0, %1" : "=v"(e0) : "v"(x0));
            asm("v_exp_f32 %0, %1" : "=v"(e1) : "v"(x1));
            dsum[r0] += e0; dsum[r1] += e1;
            unsigned int pk;
            asm("v_cvt_pk_bf16_f32 %0, %1, %2" : "=v"(pk) : "v"(e0), "v"(e1));
            const int rw0 = 32 * qh + (r0 & 3) + 8 * (r0 >> 2) + 4 * g;
            const int rw1 = rw0 + 1;
            Wt[rw0 * 64 + 8 * (slotbase ^ (rw0 & 7)) + crem] = (unsigned short)(pk & 0xFFFFu);
            Wt[rw1 * 64 + 8 * (slotbase ^ (rw1 & 7)) + crem] = (unsigned short)(pk >> 16);
        }
        __syncthreads();   // barC: W visible

        // ---- PV: 2 independent accumulator chains ----
        {
            short8_t w0 = *(const short8_t*)&Wt[offA[0]];
            short8_t v0 = *(const short8_t*)&Vt[offB[0]];
            short8_t w1 = *(const short8_t*)&Wt[offA[1]];
            short8_t v1 = *(const short8_t*)&Vt[offB[1]];
            short8_t w2 = *(const short8_t*)&Wt[offA[2]];
            short8_t v2 = *(const short8_t*)&Vt[offB[2]];
            short8_t w3 = *(const short8_t*)&Wt[offA[3]];
            short8_t v3 = *(const short8_t*)&Vt[offB[3]];
            oaccA = __builtin_amdgcn_mfma_f32_32x32x16_bf16(w0, v0, oaccA, 0, 0, 0);
            oaccB = __builtin_amdgcn_mfma_f32_32x32x16_bf16(w2, v2, oaccB, 0, 0, 0);
            oaccA = __builtin_amdgcn_mfma_f32_32x32x16_bf16(w1, v1, oaccA, 0, 0, 0);
            oaccB = __builtin_amdgcn_mfma_f32_32x32x16_bf16(w3, v3, oaccB, 0, 0, 0);
        }
    }
#undef LOADT

    // ---- epilogue: denom reduce + normalize + scatter (zeros for masked) ----
#pragma unroll
    for (int r = 0; r < 16; ++r) {
        float s = dsum[r];
        s += __shfl_xor(s, 1); s += __shfl_xor(s, 2); s += __shfl_xor(s, 4);
        s += __shfl_xor(s, 8); s += __shfl_xor(s, 16);
        dsum[r] = s;
    }
    __syncthreads();   // last tile's frag reads done before dpart reuse
    if ((l & 31) == 0) {
#pragma unroll
        for (int r = 0; r < 16; ++r)
            dpart[kh][32 * qh + (r & 3) + 8 * (r >> 2) + 4 * g] = dsum[r];
    }
    __syncthreads();
    float* Op = Out + plane_f;
#pragma unroll
    for (int r = 0; r < 16; ++r) {
        const int rowq = 32 * qh + (r & 3) + 8 * (r >> 2) + 4 * g;
        const int jq = q0 + rowq;
        const float den = EPS_ + dpart[0][rowq] + dpart[1][rowq];
        const float val = (jq < kcnt) ? (oaccA[r] + oaccB[r]) / den : 0.0f;
        Op[(size_t)qidx_s[rowq] * D_ + keycol] = val;
    }
}

extern "C" void kernel_launch(void* const* d_in, const int* in_sizes, int n_in,
                              void* d_out, int out_size, void* d_ws, size_t ws_size,
                              hipStream_t stream) {
    (void)n_in; (void)out_size; (void)in_sizes; (void)ws_size;
    const float* Q = (const float*)d_in[0];
    const float* K = (const float*)d_in[1];
    const float* V = (const float*)d_in[2];
    const void* mask = d_in[3];
    unsigned char* wsb = (unsigned char*)d_ws;

    dim3 cg(N_ / 64, 32);
    convert_kernel<<<cg, 256, 0, stream>>>(K, V, mask, wsb);
    hept_mfma_kernel<<<1024, 256, 0, stream>>>(Q, wsb, (float*)d_out);
}

// Round 10
// 158.758 us; speedup vs baseline: 1.0034x; 1.0034x over previous
//
#include <hip/hip_runtime.h>

typedef short short8_t __attribute__((ext_vector_type(8)));
typedef float floatx16 __attribute__((ext_vector_type(16)));

#define H_ 8
#define B_ 4
#define N_ 2048
#define D_ 64
#define EPS_ 0.0009765625f
#define LOG2E 1.44269504088896340736f

// ---- ws layout (bytes) ----
#define CNT_OFF   0                      // 4 int
#define IDX_OFF   256                    // [4][2048] int: unmasked indices
#define ZIDX_OFF  33024                  // [4][2048] int: masked indices
#define KHI_OFF   65792                  // [32][2048][64] bf16 (K*log2e hi)
#define KLO_OFF   (KHI_OFF + 8388608)
#define VT_OFF    (KLO_OFF + 8388608)    // [32][64][2048] bf16 V^T
#define K2_OFF    (VT_OFF + 8388608)     // [32][2048] f32 (-0.5*log2e*k2)

// split a pair of floats into bf16 hi + bf16 residual-lo words via cvt_pk
__device__ __forceinline__ void bfsplit2(float a0, float a1,
                                         unsigned int& hi, unsigned int& lo) {
    unsigned int ph;
    asm("v_cvt_pk_bf16_f32 %0, %1, %2" : "=v"(ph) : "v"(a0), "v"(a1));
    const float h0 = __uint_as_float(ph << 16);
    const float h1 = __uint_as_float(ph & 0xFFFF0000u);
    const float r0 = a0 - h0, r1 = a1 - h1;
    unsigned int pl;
    asm("v_cvt_pk_bf16_f32 %0, %1, %2" : "=v"(pl) : "v"(r0), "v"(r1));
    hi = ph; lo = pl;
}

// ---------------------------------------------------------------------------
// Convert kernel with inline mask compaction (parallel shfl-up scan).
// Grid (32 j-tiles, 32 planes). Each block: detect mask format, wave-scan
// prefix of its batch's mask, gather its 64-key window, convert
// K -> bf16 hi/lo of K*log2e, V -> bf16 V^T, k2 -> -0.5*log2e*k2.
// Blocks (j0==0, p<4) publish cnt/idx/zidx for the attn kernel.
// ---------------------------------------------------------------------------
__global__ __launch_bounds__(256) void convert_kernel(
    const float* __restrict__ Kg, const float* __restrict__ Vg,
    const void* __restrict__ mask, unsigned char* __restrict__ ws) {
    __shared__ int okInt, okFloat;
    __shared__ int wsum[4];
    __shared__ int lidx[64];
    __shared__ unsigned short Vb[64][68];   // stride 68 shorts: u32-aligned rows

    const int p = blockIdx.y;
    const int head = p >> 2, b = p & 3;
    const int j0 = blockIdx.x * 64;
    const int t = threadIdx.x;

    // ---- mask format detection (words [0,512) valid under u8/i32/f32) ----
    if (t == 0) { okInt = 1; okFloat = 1; }
    __syncthreads();
    {
        const unsigned int* w = (const unsigned int*)mask;
        int badI = 0, badF = 0;
        for (int i = t; i < 512; i += 256) {
            const unsigned int x = w[i];
            if (x > 1u) badI = 1;
            if (x != 0u && x != 0x3F800000u) badF = 1;
        }
        if (badI) atomicAnd(&okInt, 0);
        if (badF) atomicAnd(&okFloat, 0);
    }
    __syncthreads();

    // ---- per-thread mask bits for batch b ----
    int loc[8];
    const int e0 = b * N_ + t * 8;
    if (okInt) {
        const int* q = (const int*)mask;
#pragma unroll
        for (int i = 0; i < 8; ++i) loc[i] = (q[e0 + i] != 0) ? 1 : 0;
    } else if (okFloat) {
        const float* q = (const float*)mask;
#pragma unroll
        for (int i = 0; i < 8; ++i) loc[i] = (q[e0 + i] != 0.0f) ? 1 : 0;
    } else {
        const unsigned char* q = (const unsigned char*)mask;
#pragma unroll
        for (int i = 0; i < 8; ++i) loc[i] = q[e0 + i] ? 1 : 0;
    }
    int c = 0;
#pragma unroll
    for (int i = 0; i < 8; ++i) c += loc[i];

    // ---- parallel exclusive prefix over 256 threads ----
    int inc = c;
#pragma unroll
    for (int d = 1; d < 64; d <<= 1) {
        const int y = __shfl_up(inc, d);
        if ((t & 63) >= d) inc += y;
    }
    if ((t & 63) == 63) wsum[t >> 6] = inc;
    __syncthreads();
    int woff = 0;
#pragma unroll
    for (int i = 0; i < 4; ++i) woff += (i < (t >> 6)) ? wsum[i] : 0;
    const int preE = woff + inc - c;                       // excl prefix of ones
    const int kcnt = wsum[0] + wsum[1] + wsum[2] + wsum[3];
    const int zpreE = 8 * t - preE;                        // excl prefix of zeros

    // ---- designated blocks publish cnt / idx / zidx for attn ----
    if (j0 == 0 && p < 4) {
        int* ob = (int*)(ws + IDX_OFF) + b * N_;
        int* zb = (int*)(ws + ZIDX_OFF) + b * N_;
        int u = preE, z = zpreE;
#pragma unroll
        for (int i = 0; i < 8; ++i) {
            if (loc[i]) ob[u++] = t * 8 + i;
            else        zb[z++] = t * 8 + i;
        }
        if (t == 0) ((int*)(ws + CNT_OFF))[b] = kcnt;
    }
    if (j0 >= kcnt) return;   // uniform: this key tile never read

    // ---- gather this block's 64-key window into lidx ----
    {
        int u = preE;
#pragma unroll
        for (int i = 0; i < 8; ++i) {
            if (loc[i]) {
                if ((unsigned)(u - j0) < 64u) lidx[u - j0] = t * 8 + i;
                ++u;
            }
        }
    }
    __syncthreads();

    // ---- conversion ----
    const int jl = t >> 2, c4 = t & 3;
    const int j = j0 + jl;
    const size_t plane_f = (size_t)head * ((size_t)B_ * N_ * D_) + (size_t)b * (N_ * D_);

    float kv[16], vv[16];
    if (j < kcnt) {
        const int ki = lidx[jl];
        const float4* kr = (const float4*)(Kg + plane_f + (size_t)ki * D_ + 16 * c4);
        const float4* vr = (const float4*)(Vg + plane_f + (size_t)ki * D_ + 16 * c4);
#pragma unroll
        for (int i = 0; i < 4; ++i) {
            float4 a = kr[i]; float4 v = vr[i];
            kv[4*i] = a.x; kv[4*i+1] = a.y; kv[4*i+2] = a.z; kv[4*i+3] = a.w;
            vv[4*i] = v.x; vv[4*i+1] = v.y; vv[4*i+2] = v.z; vv[4*i+3] = v.w;
        }
    } else {
#pragma unroll
        for (int i = 0; i < 16; ++i) { kv[i] = 0.f; vv[i] = 0.f; }
    }
    float k2 = 0.f;
    unsigned int khi[8], klo[8];
#pragma unroll
    for (int i = 0; i < 8; ++i) {
        const float a0 = kv[2*i], a1 = kv[2*i+1];
        k2 = fmaf(a0, a0, k2); k2 = fmaf(a1, a1, k2);
        bfsplit2(a0 * LOG2E, a1 * LOG2E, khi[i], klo[i]);   // K pre-scaled by log2e
    }
    k2 += __shfl_xor(k2, 1);
    k2 += __shfl_xor(k2, 2);
    {
        unsigned char* dh = ws + KHI_OFF + ((size_t)p * N_ + j) * 128 + 32 * c4;
        unsigned char* dl = ws + KLO_OFF + ((size_t)p * N_ + j) * 128 + 32 * c4;
        ((uint4*)dh)[0] = make_uint4(khi[0], khi[1], khi[2], khi[3]);
        ((uint4*)dh)[1] = make_uint4(khi[4], khi[5], khi[6], khi[7]);
        ((uint4*)dl)[0] = make_uint4(klo[0], klo[1], klo[2], klo[3]);
        ((uint4*)dl)[1] = make_uint4(klo[4], klo[5], klo[6], klo[7]);
        if (c4 == 0) ((float*)(ws + K2_OFF))[(size_t)p * N_ + j] = -0.5f * LOG2E * k2;
    }
#pragma unroll
    for (int i = 0; i < 8; ++i) {   // V -> bf16 (packed pair writes)
        unsigned int pv;
        asm("v_cvt_pk_bf16_f32 %0, %1, %2" : "=v"(pv) : "v"(vv[2*i]), "v"(vv[2*i+1]));
        *(unsigned int*)&Vb[jl][16 * c4 + 2 * i] = pv;
    }
    __syncthreads();
    {   // transposed write: VT row d = jl, cols j0+16c4..+15
        unsigned int wds[8];
#pragma unroll
        for (int i = 0; i < 8; ++i)
            wds[i] = (unsigned int)Vb[16*c4 + 2*i][jl] | ((unsigned int)Vb[16*c4 + 2*i + 1][jl] << 16);
        unsigned char* dv = ws + VT_OFF + ((size_t)p * 64 + jl) * ((size_t)N_ * 2) + (size_t)(j0 + 16 * c4) * 2;
        ((uint4*)dv)[0] = make_uint4(wds[0], wds[1], wds[2], wds[3]);
        ((uint4*)dv)[1] = make_uint4(wds[4], wds[5], wds[6], wds[7]);
    }
}

// ---------------------------------------------------------------------------
// MFMA attention, compacted q & k, fused zero-fill epilogue.
// r8 register discipline: launch_bounds(256,3), Q frags re-read from LDS per
// tile, single PV accumulator. QK split-bf16 into TWO accumulator chains
// (HH+LH / HL). exp via raw v_exp_f32 (K pre-scaled by log2e); pads masked
// via k2=-1e30; W -> bf16 via v_cvt_pk_bf16_f32.
// C/D layout (m74/m101): col=lane&31, row=(reg&3)+8*(reg>>2)+4*(lane>>5).
// ---------------------------------------------------------------------------
__global__ __launch_bounds__(256, 3) void hept_mfma_kernel(
    const float* __restrict__ Qg, const unsigned char* __restrict__ ws,
    float* __restrict__ Out) {
    __shared__ __align__(16) unsigned short Qhi[4096], Qlo[4096], Khi[4096],
                                            Klo[4096], Vt[4096], Wt[4096];
    __shared__ float q2s[64], k2t[64], dpart[2][64];
    __shared__ int qidx_s[64];

    const int t = threadIdx.x;
    const int l = t & 63;
    const int w = t >> 6;
    const int qh = w >> 1, kh = w & 1;

    // XCD swizzle: 4 consecutive planes per XCD
    const int cid = blockIdx.x;
    const int swz = (cid & 7) * 128 + (cid >> 3);
    const int p = swz >> 5;
    const int qb = swz & 31;
    const int head = p >> 2, b = p & 3;
    const int q0 = qb * 64;

    const int kcnt = ((const int*)(ws + CNT_OFF))[b];
    const int* idxb = (const int*)(ws + IDX_OFF) + b * N_;
    const int* zidxb = (const int*)(ws + ZIDX_OFF) + b * N_;
    const bool active = (q0 < kcnt);
    const int nt = active ? ((kcnt + 63) >> 6) : 0;

    const size_t plane_f = (size_t)head * ((size_t)B_ * N_ * D_) + (size_t)b * (N_ * D_);
    const unsigned short* khi_g = (const unsigned short*)(ws + KHI_OFF) + (size_t)p * ((size_t)N_ * 64);
    const unsigned short* klo_g = (const unsigned short*)(ws + KLO_OFF) + (size_t)p * ((size_t)N_ * 64);
    const unsigned short* vt_g  = (const unsigned short*)(ws + VT_OFF)  + (size_t)p * ((size_t)64 * N_);
    const float* k2_g = (const float*)(ws + K2_OFF) + (size_t)p * N_;

    // ---- prologue: output row map; gather+split Q (active only) ----
    if (t < 64) {
        const int jq = q0 + t;
        qidx_s[t] = (jq < kcnt) ? idxb[jq] : zidxb[jq - kcnt];
    }
    if (active) {
        const int row = t >> 2, c4 = t & 3;
        const int jq = q0 + row;
        const int qi = (jq < kcnt) ? idxb[jq] : idxb[0];
        const float4* qr = (const float4*)(Qg + plane_f + (size_t)qi * D_ + 16 * c4);
        float q[16];
#pragma unroll
        for (int i = 0; i < 4; ++i) {
            float4 a = qr[i];
            q[4*i] = a.x; q[4*i+1] = a.y; q[4*i+2] = a.z; q[4*i+3] = a.w;
        }
        float q2 = 0.f;
        unsigned int hi[8], lo[8];
#pragma unroll
        for (int i = 0; i < 8; ++i) {
            const float a0 = q[2*i], a1 = q[2*i+1];
            q2 = fmaf(a0, a0, q2); q2 = fmaf(a1, a1, q2);
            bfsplit2(a0, a1, hi[i], lo[i]);          // Q stays UNSCALED
        }
        q2 += __shfl_xor(q2, 1);
        q2 += __shfl_xor(q2, 2);
        if (c4 == 0) q2s[row] = -0.5f * LOG2E * q2;
        const int s0 = (2 * c4) ^ (row & 7);
        const int s1 = (2 * c4 + 1) ^ (row & 7);
        *(uint4*)&Qhi[row * 64 + 8 * s0] = make_uint4(hi[0], hi[1], hi[2], hi[3]);
        *(uint4*)&Qhi[row * 64 + 8 * s1] = make_uint4(hi[4], hi[5], hi[6], hi[7]);
        *(uint4*)&Qlo[row * 64 + 8 * s0] = make_uint4(lo[0], lo[1], lo[2], lo[3]);
        *(uint4*)&Qlo[row * 64 + 8 * s1] = make_uint4(lo[4], lo[5], lo[6], lo[7]);
    }
    __syncthreads();

    // per-lane frag offsets (ushort index); identical pattern A and B sides
    const int rowA = 32 * qh + (l & 31);
    const int rowB = 32 * kh + (l & 31);
    const int g = l >> 5;
    int offA[4], offB[4];
#pragma unroll
    for (int ks = 0; ks < 4; ++ks) {
        offA[ks] = rowA * 64 + 8 * ((2 * ks + g) ^ (rowA & 7));
        offB[ks] = rowB * 64 + 8 * ((2 * ks + g) ^ (rowB & 7));
    }
    float q2r[16];
#pragma unroll
    for (int r = 0; r < 16; ++r)
        q2r[r] = q2s[32 * qh + (r & 3) + 8 * (r >> 2) + 4 * g];

    // staging geometry: wave w covers 1KB chunks {2w,2w+1}; pre-swizzled src
    const int rch = l >> 3;
    const int sl8 = (l & 7) ^ rch;
    const int ch0 = 2 * w, ch1 = 2 * w + 1;
    const unsigned short* srcK0 = khi_g + (size_t)(ch0 * 8 + rch) * 64 + 8 * sl8;
    const unsigned short* srcK1 = khi_g + (size_t)(ch1 * 8 + rch) * 64 + 8 * sl8;
    const unsigned short* srcL0 = klo_g + (size_t)(ch0 * 8 + rch) * 64 + 8 * sl8;
    const unsigned short* srcL1 = klo_g + (size_t)(ch1 * 8 + rch) * 64 + 8 * sl8;
    const unsigned short* srcV0 = vt_g + (size_t)(ch0 * 8 + rch) * N_ + 8 * sl8;
    const unsigned short* srcV1 = vt_g + (size_t)(ch1 * 8 + rch) * N_ + 8 * sl8;
    const int dstA = ch0 * 512 + 8 * l;
    const int dstB = ch1 * 512 + 8 * l;

    floatx16 oacc;
    float dsum[16];
#pragma unroll
    for (int r = 0; r < 16; ++r) { oacc[r] = 0.f; dsum[r] = 0.f; }
    const int keycol = 32 * kh + (l & 31);
    const int slotbase = keycol >> 3;
    const int crem = keycol & 7;

    uint4 rA0, rA1, rB0, rB1, rC0, rC1;
    float rk2;
#define LOADT(kt_) do { \
        const size_t o_ = (size_t)(kt_) * 4096; \
        const size_t ov_ = (size_t)(kt_) * 64; \
        rA0 = *(const uint4*)(srcK0 + o_); rA1 = *(const uint4*)(srcK1 + o_); \
        rB0 = *(const uint4*)(srcL0 + o_); rB1 = *(const uint4*)(srcL1 + o_); \
        rC0 = *(const uint4*)(srcV0 + ov_); rC1 = *(const uint4*)(srcV1 + ov_); \
        rk2 = -1e30f; \
        if (t < 64) { \
            const int pos_ = (kt_) * 64 + t; \
            const float v_ = k2_g[pos_]; \
            rk2 = (pos_ < kcnt) ? v_ : -1e30f; \
        } \
    } while (0)

    if (nt > 0) LOADT(0);
    for (int kt = 0; kt < nt; ++kt) {
        __syncthreads();   // barA: prev tile's frag reads done -> LDS free
        *(uint4*)&Khi[dstA] = rA0;  *(uint4*)&Khi[dstB] = rA1;
        *(uint4*)&Klo[dstA] = rB0;  *(uint4*)&Klo[dstB] = rB1;
        *(uint4*)&Vt[dstA]  = rC0;  *(uint4*)&Vt[dstB]  = rC1;
        if (t < 64) k2t[t] = rk2;
        __syncthreads();   // barB: staged
        if (kt + 1 < nt) LOADT(kt + 1);  // prefetch hides under QK+exp

        // ---- QK^T: split bf16, TWO accumulator chains ----
        floatx16 aA, aB;
#pragma unroll
        for (int r = 0; r < 16; ++r) { aA[r] = 0.f; aB[r] = 0.f; }
#pragma unroll
        for (int ks = 0; ks < 4; ++ks) {
            short8_t qH = *(const short8_t*)&Qhi[offA[ks]];
            short8_t qL = *(const short8_t*)&Qlo[offA[ks]];
            short8_t kH = *(const short8_t*)&Khi[offB[ks]];
            short8_t kL = *(const short8_t*)&Klo[offB[ks]];
            aA = __builtin_amdgcn_mfma_f32_32x32x16_bf16(qH, kH, aA, 0, 0, 0);
            aB = __builtin_amdgcn_mfma_f32_32x32x16_bf16(qH, kL, aB, 0, 0, 0);
            aA = __builtin_amdgcn_mfma_f32_32x32x16_bf16(qL, kH, aA, 0, 0, 0);
        }

        // ---- w = 2^(qk*log2e - (q2+k2)*log2e/2); pads have k2=-1e30 ----
        const float k2v = k2t[keycol];
#pragma unroll
        for (int i = 0; i < 8; ++i) {
            const int r0 = 2 * i, r1 = 2 * i + 1;
            const float x0 = (aA[r0] + aB[r0]) + (q2r[r0] + k2v);
            const float x1 = (aA[r1] + aB[r1]) + (q2r[r1] + k2v);
            float e0, e1;
            asm("v_exp_f32 %0, %1" : "=v"(e0) : "v"(x0));
            asm("v_exp_f32 %0, %1" : "=v"(e1) : "v"(x1));
            dsum[r0] += e0; dsum[r1] += e1;
            unsigned int pk;
            asm("v_cvt_pk_bf16_f32 %0, %1, %2" : "=v"(pk) : "v"(e0), "v"(e1));
            const int rw0 = 32 * qh + (r0 & 3) + 8 * (r0 >> 2) + 4 * g;
            const int rw1 = rw0 + 1;
            Wt[rw0 * 64 + 8 * (slotbase ^ (rw0 & 7)) + crem] = (unsigned short)(pk & 0xFFFFu);
            Wt[rw1 * 64 + 8 * (slotbase ^ (rw1 & 7)) + crem] = (unsigned short)(pk >> 16);
        }
        __syncthreads();   // barC: W visible

        // ---- PV: single accumulator (register-lean) ----
#pragma unroll
        for (int ks = 0; ks < 4; ++ks) {
            short8_t aW = *(const short8_t*)&Wt[offA[ks]];
            short8_t bV = *(const short8_t*)&Vt[offB[ks]];
            oacc = __builtin_amdgcn_mfma_f32_32x32x16_bf16(aW, bV, oacc, 0, 0, 0);
        }
    }
#undef LOADT

    // ---- epilogue: denom reduce + normalize + scatter (zeros for masked) ----
#pragma unroll
    for (int r = 0; r < 16; ++r) {
        float s = dsum[r];
        s += __shfl_xor(s, 1); s += __shfl_xor(s, 2); s += __shfl_xor(s, 4);
        s += __shfl_xor(s, 8); s += __shfl_xor(s, 16);
        dsum[r] = s;
    }
    __syncthreads();   // last tile's frag reads done before dpart reuse
    if ((l & 31) == 0) {
#pragma unroll
        for (int r = 0; r < 16; ++r)
            dpart[kh][32 * qh + (r & 3) + 8 * (r >> 2) + 4 * g] = dsum[r];
    }
    __syncthreads();
    float* Op = Out + plane_f;
#pragma unroll
    for (int r = 0; r < 16; ++r) {
        const int rowq = 32 * qh + (r & 3) + 8 * (r >> 2) + 4 * g;
        const int jq = q0 + rowq;
        const float den = EPS_ + dpart[0][rowq] + dpart[1][rowq];
        const float val = (jq < kcnt) ? oacc[r] / den : 0.0f;
        Op[(size_t)qidx_s[rowq] * D_ + keycol] = val;
    }
}

extern "C" void kernel_launch(void* const* d_in, const int* in_sizes, int n_in,
                              void* d_out, int out_size, void* d_ws, size_t ws_size,
                              hipStream_t stream) {
    (void)n_in; (void)out_size; (void)in_sizes; (void)ws_size;
    const float* Q = (const float*)d_in[0];
    const float* K = (const float*)d_in[1];
    const float* V = (const float*)d_in[2];
    const void* mask = d_in[3];
    unsigned char* wsb = (unsigned char*)d_ws;

    dim3 cg(N_ / 64, 32);
    convert_kernel<<<cg, 256, 0, stream>>>(K, V, mask, wsb);
    hept_mfma_kernel<<<1024, 256, 0, stream>>>(Q, wsb, (float*)d_out);
}